// Round 3
// baseline (84.451 us; speedup 1.0000x reference)
//
#include <hip/hip_runtime.h>

#define NUM_INPUTS 4096
#define NUM_LEAVES 2048
#define ROWS_PER_BLOCK 8
#define BLK 64

typedef const __attribute__((address_space(1))) void* gas_ptr;
typedef __attribute__((address_space(3))) void* las_ptr;

// out[b, l] = x[b, idx[l]]
// Wave-autonomous pipeline: 1 wave per block, 2x16KiB LDS double buffer,
// counted s_waitcnt vmcnt(16) (never 0 in steady state), zero barriers.
// Row r+1's global_load_lds stay in flight across row r's gather+store,
// so HBM read issue never idles (kills the stage/store phase convoy).
__global__ __launch_bounds__(BLK) void FrozenInputToLeaf_wavepipe(
    const float* __restrict__ x,
    const int* __restrict__ idx,
    float* __restrict__ out) {
    __shared__ float buf[2][NUM_INPUTS];  // 32 KiB -> 5 blocks/CU

    const int lane = threadIdx.x;
    const size_t row0 = (size_t)blockIdx.x * ROWS_PER_BLOCK;

    // Per-lane indices, loaded once for all 8 rows. Store j covers leaves
    // (j*64+lane)*4 .. +3, so lane needs int4 iv[j*64+lane] (coalesced).
    const int4* __restrict__ iv = (const int4*)idx;
    int4 ireg[8];
#pragma unroll
    for (int j = 0; j < 8; ++j) ireg[j] = iv[j * 64 + lane];

    // Prologue: stage row0 into buf[0]. 16 KiB = 16 x (64 lanes x 16B).
    {
        const float* __restrict__ src = x + row0 * NUM_INPUTS;
#pragma unroll
        for (int i = 0; i < 16; ++i) {
            const int e = (i * 64 + lane) * 4;
            __builtin_amdgcn_global_load_lds((gas_ptr)(src + e),
                                             (las_ptr)(&buf[0][e]), 16, 0, 0);
        }
    }

#pragma unroll
    for (int r = 0; r < ROWS_PER_BLOCK; ++r) {
        const int p = r & 1;  // compile-time after unroll
        if (r + 1 < ROWS_PER_BLOCK) {
            // Issue next row's loads BEFORE waiting on this row's.
            const float* __restrict__ src = x + (row0 + r + 1) * NUM_INPUTS;
#pragma unroll
            for (int i = 0; i < 16; ++i) {
                const int e = (i * 64 + lane) * 4;
                __builtin_amdgcn_global_load_lds((gas_ptr)(src + e),
                                                 (las_ptr)(&buf[p ^ 1][e]), 16, 0, 0);
            }
            // FIFO at this point: 16 loads(r) [oldest], 8 stores(r-1), 16 loads(r+1).
            // vmcnt(16) retires loads(r) (+ old stores); prefetch stays in flight.
            asm volatile("s_waitcnt vmcnt(16)" ::: "memory");
        } else {
            asm volatile("s_waitcnt vmcnt(0)" ::: "memory");  // once per wave
        }
        __builtin_amdgcn_sched_barrier(0);  // keep ds_reads below the waitcnt

        const float* __restrict__ cur = buf[p];
        float4* __restrict__ ov = (float4*)(out + (row0 + r) * NUM_LEAVES);
#pragma unroll
        for (int j = 0; j < 8; ++j) {
            float4 v;
            v.x = cur[ireg[j].x];
            v.y = cur[ireg[j].y];
            v.z = cur[ireg[j].z];
            v.w = cur[ireg[j].w];
            ov[j * 64 + lane] = v;  // 1 KiB contiguous per wave-instr
        }
    }
}

extern "C" void kernel_launch(void* const* d_in, const int* in_sizes, int n_in,
                              void* d_out, int out_size, void* d_ws, size_t ws_size,
                              hipStream_t stream) {
    const float* x = (const float*)d_in[0];
    const int* idx = (const int*)d_in[1];
    float* out = (float*)d_out;

    const int batch = in_sizes[0] / NUM_INPUTS;   // 16384
    const int grid = batch / ROWS_PER_BLOCK;      // 2048 blocks, 8 rows each

    FrozenInputToLeaf_wavepipe<<<grid, BLK, 0, stream>>>(x, idx, out);
}

// Round 4
// 81.818 us; speedup vs baseline: 1.0322x; 1.0322x over previous
//
#include <hip/hip_runtime.h>

#define NUM_INPUTS 4096
#define NUM_LEAVES 2048
#define ROWS_PER_BLOCK 2
#define BLK 256

typedef const __attribute__((address_space(1))) void* gas_ptr;
typedef __attribute__((address_space(3))) void* las_ptr;
typedef float vfloat4 __attribute__((ext_vector_type(4)));

// out[b, l] = x[b, idx[l]]
// R1 structure (2 rows/block, global_load_lds staging, LDS gather, coalesced
// stores) + non-temporal cache policy on both streams: x is read exactly once
// and out written exactly once, so L2/L3 allocation is pure overhead.
__global__ __launch_bounds__(BLK) void FrozenInputToLeaf_gather_nt(
    const float* __restrict__ x,
    const int* __restrict__ idx,
    float* __restrict__ out) {
    __shared__ float rows[ROWS_PER_BLOCK][NUM_INPUTS];

    const int t = threadIdx.x;
    const size_t b0 = (size_t)blockIdx.x * ROWS_PER_BLOCK;

    // Indices: 8 KiB total, reused by all blocks — keep these CACHED (default).
    const int4* __restrict__ iv = (const int4*)idx;
    const int4 i0 = iv[t * 2 + 0];
    const int4 i1 = iv[t * 2 + 1];

    // Stage rows global->LDS with NT policy (aux=2: CPol NT bit on gfx94x/950).
#pragma unroll
    for (int r = 0; r < ROWS_PER_BLOCK; ++r) {
        const float* __restrict__ src = x + (b0 + r) * NUM_INPUTS;
#pragma unroll
        for (int j = 0; j < 4; ++j) {
            const int e = (j * BLK + threadIdx.x) * 4;
            __builtin_amdgcn_global_load_lds((gas_ptr)(src + e),
                                             (las_ptr)(&rows[r][e]), 16, 0, 2);
        }
    }
    __syncthreads();

#pragma unroll
    for (int r = 0; r < ROWS_PER_BLOCK; ++r) {
        vfloat4 o0, o1;
        o0.x = rows[r][i0.x];
        o0.y = rows[r][i0.y];
        o0.z = rows[r][i0.z];
        o0.w = rows[r][i0.w];
        o1.x = rows[r][i1.x];
        o1.y = rows[r][i1.y];
        o1.z = rows[r][i1.z];
        o1.w = rows[r][i1.w];

        vfloat4* __restrict__ ov = (vfloat4*)(out + (b0 + r) * NUM_LEAVES);
        __builtin_nontemporal_store(o0, &ov[t * 2 + 0]);
        __builtin_nontemporal_store(o1, &ov[t * 2 + 1]);
    }
}

extern "C" void kernel_launch(void* const* d_in, const int* in_sizes, int n_in,
                              void* d_out, int out_size, void* d_ws, size_t ws_size,
                              hipStream_t stream) {
    const float* x = (const float*)d_in[0];
    const int* idx = (const int*)d_in[1];
    float* out = (float*)d_out;

    const int batch = in_sizes[0] / NUM_INPUTS;  // 16384
    const int grid = batch / ROWS_PER_BLOCK;     // 8192

    FrozenInputToLeaf_gather_nt<<<grid, BLK, 0, stream>>>(x, idx, out);
}

// Round 5
// 77.747 us; speedup vs baseline: 1.0862x; 1.0524x over previous
//
#include <hip/hip_runtime.h>

#define NUM_INPUTS 4096
#define NUM_LEAVES 2048
#define ROWS_PER_BLOCK 2
#define BLK 256

typedef const __attribute__((address_space(1))) void* gas_ptr;
typedef __attribute__((address_space(3))) void* las_ptr;
typedef float vfloat4 __attribute__((ext_vector_type(4)));

// out[b, l] = x[b, idx[l]]
// R1 structure (best: 74.5us): global_load_lds staging with DEFAULT cache
// policy, LDS gather, coalesced stores — but stores are non-temporal to
// suppress L2 write-allocate (RFO) on the use-once out stream.
__global__ __launch_bounds__(BLK) void FrozenInputToLeaf_gather_ntst(
    const float* __restrict__ x,
    const int* __restrict__ idx,
    float* __restrict__ out) {
    __shared__ float rows[ROWS_PER_BLOCK][NUM_INPUTS];

    const int t = threadIdx.x;
    const size_t b0 = (size_t)blockIdx.x * ROWS_PER_BLOCK;

    const int4* __restrict__ iv = (const int4*)idx;
    const int4 i0 = iv[t * 2 + 0];
    const int4 i1 = iv[t * 2 + 1];

    // Staging: default cache policy (aux=0) — R3 showed NT here regresses.
#pragma unroll
    for (int r = 0; r < ROWS_PER_BLOCK; ++r) {
        const float* __restrict__ src = x + (b0 + r) * NUM_INPUTS;
#pragma unroll
        for (int j = 0; j < 4; ++j) {
            const int e = (j * BLK + threadIdx.x) * 4;
            __builtin_amdgcn_global_load_lds((gas_ptr)(src + e),
                                             (las_ptr)(&rows[r][e]), 16, 0, 0);
        }
    }
    __syncthreads();

#pragma unroll
    for (int r = 0; r < ROWS_PER_BLOCK; ++r) {
        vfloat4 o0, o1;
        o0.x = rows[r][i0.x];
        o0.y = rows[r][i0.y];
        o0.z = rows[r][i0.z];
        o0.w = rows[r][i0.w];
        o1.x = rows[r][i1.x];
        o1.y = rows[r][i1.y];
        o1.z = rows[r][i1.z];
        o1.w = rows[r][i1.w];

        vfloat4* __restrict__ ov = (vfloat4*)(out + (b0 + r) * NUM_LEAVES);
        __builtin_nontemporal_store(o0, &ov[t * 2 + 0]);
        __builtin_nontemporal_store(o1, &ov[t * 2 + 1]);
    }
}

extern "C" void kernel_launch(void* const* d_in, const int* in_sizes, int n_in,
                              void* d_out, int out_size, void* d_ws, size_t ws_size,
                              hipStream_t stream) {
    const float* x = (const float*)d_in[0];
    const int* idx = (const int*)d_in[1];
    float* out = (float*)d_out;

    const int batch = in_sizes[0] / NUM_INPUTS;  // 16384
    const int grid = batch / ROWS_PER_BLOCK;     // 8192

    FrozenInputToLeaf_gather_ntst<<<grid, BLK, 0, stream>>>(x, idx, out);
}